// Round 3
// baseline (36.945 us; speedup 1.0000x reference)
//
#include <hip/hip_runtime.h>

#define B_   16
#define T_   10
#define D_   256
#define MI_  32
#define MO_  16
#define RES_ 200
#define XCHUNK 20
#define XHALF  (XCHUNK / 2)             // 10 x per half-block
#define NCHUNK (RES_ / XCHUNK)          // 10
#define OG_    4                        // o-groups in kernel A
#define OPG    (MO_ / OG_)              // 4 o per A block
#define CS_STRIDE (2 * MO_ * D_)        // 8192 floats per bt
#define CS_BYTES ((size_t)B_ * T_ * CS_STRIDE * sizeof(float))  // 5.24 MB

// ---------- Kernel A: complex contraction -> C,S planes in ws --------------
// grid 640 = bt*4 + og ; block 256 = h. Each block does 4 of the 16 o's.
__global__ __launch_bounds__(256) void spectral_cs(
    const float* __restrict__ v,
    const float* __restrict__ w_real,
    const float* __restrict__ w_imag,
    float* __restrict__ ws)
{
    const int blk = blockIdx.x;
    const int bt  = blk >> 2;
    const int og  = blk & 3;
    const int t   = bt % T_;
    const int d   = threadIdx.x;

    __shared__ float s_w[OPG][2][MI_];   // [o_local][re/im][m], 1 KB

    const float* wrt = w_real + (size_t)(t * MO_ + og * OPG) * MI_;
    const float* wit = w_imag + (size_t)(t * MO_ + og * OPG) * MI_;
    {   // 256 entries, one per thread
        int ol = threadIdx.x >> 6;
        int ri = (threadIdx.x >> 5) & 1;
        int m  = threadIdx.x & 31;
        s_w[ol][ri][m] = ri ? wit[ol * MI_ + m] : wrt[ol * MI_ + m];
    }
    __syncthreads();

    float rr[MI_], ii[MI_];
    const float4* vp = reinterpret_cast<const float4*>(
        v + (size_t)(bt * D_ + d) * (2 * MI_));
    #pragma unroll
    for (int j = 0; j < MI_ / 4; ++j) {
        float4 q = vp[j];
        rr[4*j+0]=q.x; rr[4*j+1]=q.y; rr[4*j+2]=q.z; rr[4*j+3]=q.w;
    }
    #pragma unroll
    for (int j = 0; j < MI_ / 4; ++j) {
        float4 q = vp[MI_/4 + j];
        ii[4*j+0]=q.x; ii[4*j+1]=q.y; ii[4*j+2]=q.z; ii[4*j+3]=q.w;
    }

    float* wsp = ws + (size_t)bt * CS_STRIDE;
    #pragma unroll
    for (int ol = 0; ol < OPG; ++ol) {
        float c = 0.f, s = 0.f;
        #pragma unroll
        for (int mq = 0; mq < MI_ / 4; ++mq) {
            float4 a4 = *reinterpret_cast<const float4*>(&s_w[ol][0][mq*4]);
            float4 b4 = *reinterpret_cast<const float4*>(&s_w[ol][1][mq*4]);
            c = fmaf(rr[mq*4+0], a4.x, c); c = fmaf(-ii[mq*4+0], b4.x, c);
            s = fmaf(rr[mq*4+0], b4.x, s); s = fmaf( ii[mq*4+0], a4.x, s);
            c = fmaf(rr[mq*4+1], a4.y, c); c = fmaf(-ii[mq*4+1], b4.y, c);
            s = fmaf(rr[mq*4+1], b4.y, s); s = fmaf( ii[mq*4+1], a4.y, s);
            c = fmaf(rr[mq*4+2], a4.z, c); c = fmaf(-ii[mq*4+2], b4.z, c);
            s = fmaf(rr[mq*4+2], b4.z, s); s = fmaf( ii[mq*4+2], a4.z, s);
            c = fmaf(rr[mq*4+3], a4.w, c); c = fmaf(-ii[mq*4+3], b4.w, c);
            s = fmaf(rr[mq*4+3], b4.w, s); s = fmaf( ii[mq*4+3], a4.w, s);
        }
        const int o = og * OPG + ol;
        wsp[o * D_ + d]         = c;    // coalesced plane store
        wsp[(MO_ + o) * D_ + d] = s;
    }
}

// ---------- Kernel B: inverse transform, x-parallel, 2 h per thread --------
// grid 1600 ; block 256 = (hp 0..127) x (xs 0..1). hp covers h = 2hp, 2hp+1.
__global__ __launch_bounds__(256) void spectral_ift(
    const float* __restrict__ ws,
    float* __restrict__ out)
{
    const int blk = blockIdx.x;
    const int bt  = blk / NCHUNK;
    const int x0  = (blk % NCHUNK) * XCHUNK;
    const int hp  = threadIdx.x & 127;
    const int xs  = threadIdx.x >> 7;
    const int h0  = hp * 2;

    __shared__ float s_trig[XCHUNK][2 * MO_];  // [xl][0..15]=cos, [16..31]=-sin

    for (int idx = threadIdx.x; idx < XCHUNK * 2 * MO_; idx += 256) {
        int xl = idx >> 5;
        int q  = idx & 31;
        int o  = q & 15;
        unsigned k = (unsigned)(o * (x0 + xl)) % RES_;
        float ang = 6.28318530717958647692f * ((float)k * (1.0f / (float)RES_));
        float sv, cv;
        __sincosf(ang, &sv, &cv);
        s_trig[xl][q] = (q & 16) ? -sv : cv;
    }

    // coalesced float2 C,S loads (2 h per thread), 32 instrs, 512B/instr
    const float* wsp = ws + (size_t)bt * CS_STRIDE;
    float C0[MO_], C1[MO_], S0[MO_], S1[MO_];
    #pragma unroll
    for (int o = 0; o < MO_; ++o) {
        float2 c2 = *reinterpret_cast<const float2*>(&wsp[o * D_ + h0]);
        float2 s2 = *reinterpret_cast<const float2*>(&wsp[(MO_ + o) * D_ + h0]);
        C0[o] = c2.x; C1[o] = c2.y;
        S0[o] = s2.x; S1[o] = s2.y;
    }
    __syncthreads();

    float* op = out + ((size_t)bt * RES_ + x0 + xs * XHALF) * D_ + h0;
    #pragma unroll
    for (int xi = 0; xi < XHALF; ++xi) {
        const int xl = xs * XHALF + xi;
        float a0 = 0.f, a1 = 0.f;
        #pragma unroll
        for (int oq = 0; oq < MO_ / 4; ++oq) {
            float4 tc = *reinterpret_cast<const float4*>(&s_trig[xl][oq*4]);
            float4 ts = *reinterpret_cast<const float4*>(&s_trig[xl][MO_ + oq*4]);
            a0 = fmaf(C0[oq*4+0], tc.x, a0); a0 = fmaf(S0[oq*4+0], ts.x, a0);
            a1 = fmaf(C1[oq*4+0], tc.x, a1); a1 = fmaf(S1[oq*4+0], ts.x, a1);
            a0 = fmaf(C0[oq*4+1], tc.y, a0); a0 = fmaf(S0[oq*4+1], ts.y, a0);
            a1 = fmaf(C1[oq*4+1], tc.y, a1); a1 = fmaf(S1[oq*4+1], ts.y, a1);
            a0 = fmaf(C0[oq*4+2], tc.z, a0); a0 = fmaf(S0[oq*4+2], ts.z, a0);
            a1 = fmaf(C1[oq*4+2], tc.z, a1); a1 = fmaf(S1[oq*4+2], ts.z, a1);
            a0 = fmaf(C0[oq*4+3], tc.w, a0); a0 = fmaf(S0[oq*4+3], ts.w, a0);
            a1 = fmaf(C1[oq*4+3], tc.w, a1); a1 = fmaf(S1[oq*4+3], ts.w, a1);
        }
        float2 r; r.x = a0; r.y = a1;
        *reinterpret_cast<float2*>(&op[(size_t)xi * D_]) = r;
    }
}

// ---------- Fallback (ws too small): fused kernel --------------------------
__global__ __launch_bounds__(256) void spectral_fused(
    const float* __restrict__ v,
    const float* __restrict__ w_real,
    const float* __restrict__ w_imag,
    float* __restrict__ out)
{
    const int bt = blockIdx.x;
    const int t  = bt % T_;
    const int d  = threadIdx.x;

    __shared__ float s_wr[MO_ * MI_];
    __shared__ float s_wi[MO_ * MI_];
    __shared__ float s_trig[RES_][2 * MO_];

    const float* wrt = w_real + t * MO_ * MI_;
    const float* wit = w_imag + t * MO_ * MI_;
    for (int idx = threadIdx.x; idx < MO_ * MI_; idx += 256) {
        s_wr[idx] = wrt[idx];
        s_wi[idx] = wit[idx];
    }
    for (int idx = threadIdx.x; idx < RES_ * MO_; idx += 256) {
        int x = idx >> 4;
        int o = idx & 15;
        int k = (o * x) % RES_;
        float ang = 6.28318530717958647692f * ((float)k * (1.0f / (float)RES_));
        float sv, cv;
        __sincosf(ang, &sv, &cv);
        s_trig[x][o]       = cv;
        s_trig[x][o + MO_] = -sv;
    }
    __syncthreads();

    float rr[MI_], ii[MI_];
    const float4* vp = reinterpret_cast<const float4*>(
        v + (size_t)(bt * D_ + d) * (2 * MI_));
    #pragma unroll
    for (int j = 0; j < MI_ / 4; ++j) {
        float4 q = vp[j];
        rr[4*j+0]=q.x; rr[4*j+1]=q.y; rr[4*j+2]=q.z; rr[4*j+3]=q.w;
    }
    #pragma unroll
    for (int j = 0; j < MI_ / 4; ++j) {
        float4 q = vp[MI_/4 + j];
        ii[4*j+0]=q.x; ii[4*j+1]=q.y; ii[4*j+2]=q.z; ii[4*j+3]=q.w;
    }

    float C[MO_], S[MO_];
    #pragma unroll
    for (int o = 0; o < MO_; ++o) {
        float c = 0.f, s = 0.f;
        #pragma unroll
        for (int m = 0; m < MI_; ++m) {
            float a = s_wr[o * MI_ + m];
            float b = s_wi[o * MI_ + m];
            c = fmaf(rr[m], a, c);
            c = fmaf(-ii[m], b, c);
            s = fmaf(rr[m], b, s);
            s = fmaf(ii[m], a, s);
        }
        C[o] = c;
        S[o] = s;
    }

    float* op = out + (size_t)bt * RES_ * D_ + d;
    for (int x = 0; x < RES_; ++x) {
        float acc = 0.f;
        #pragma unroll
        for (int o = 0; o < MO_; ++o) {
            acc = fmaf(C[o], s_trig[x][o],       acc);
            acc = fmaf(S[o], s_trig[x][o + MO_], acc);
        }
        op[(size_t)x * D_] = acc;
    }
}

extern "C" void kernel_launch(void* const* d_in, const int* in_sizes, int n_in,
                              void* d_out, int out_size, void* d_ws, size_t ws_size,
                              hipStream_t stream) {
    const float* v  = (const float*)d_in[0];
    const float* wr = (const float*)d_in[1];
    const float* wi = (const float*)d_in[2];
    float* out = (float*)d_out;

    if (ws_size >= CS_BYTES) {
        float* ws = (float*)d_ws;
        spectral_cs <<<B_ * T_ * OG_,    256, 0, stream>>>(v, wr, wi, ws);
        spectral_ift<<<B_ * T_ * NCHUNK, 256, 0, stream>>>(ws, out);
    } else {
        spectral_fused<<<B_ * T_, 256, 0, stream>>>(v, wr, wi, out);
    }
}